// Round 13
// baseline (425.884 us; speedup 1.0000x reference)
//
#include <hip/hip_runtime.h>
#include <stdint.h>

static constexpr int BATCH  = 8;
static constexpr int SEQ    = 1024;
static constexpr int DMODEL = 1024;
static constexpr int NHEAD  = 16;

typedef __attribute__((ext_vector_type(8))) short sh8;
typedef __attribute__((ext_vector_type(4))) float fl4;

__device__ __forceinline__ uint16_t f2bf(float f) {
    union { float f; uint32_t u; } a; a.f = f;
    uint32_t r = a.u + 0x7FFFu + ((a.u >> 16) & 1u);
    return (uint16_t)(r >> 16);
}

__device__ __forceinline__ float b2f(uint16_t u) {
    union { uint32_t u; float f; } a; a.u = ((uint32_t)u) << 16; return a.f;
}

// HW packed fp32->bf16 (RNE)
__device__ __forceinline__ uint32_t cvtpk(float lo, float hi) {
    uint32_t r;
    asm("v_cvt_pk_bf16_f32 %0, %1, %2" : "=v"(r) : "v"(lo), "v"(hi));
    return r;
}

__device__ __forceinline__ sh8 pack_bf8(fl4 x0, fl4 x1) {
    union { uint32_t w[4]; sh8 v; } pk;
    pk.w[0] = cvtpk(x0[0], x0[1]); pk.w[1] = cvtpk(x0[2], x0[3]);
    pk.w[2] = cvtpk(x1[0], x1[1]); pk.w[3] = cvtpk(x1[2], x1[3]);
    return pk.v;
}

__device__ __forceinline__ fl4 mfma16(sh8 a, sh8 b, fl4 c) {
    return __builtin_amdgcn_mfma_f32_16x16x32_bf16(a, b, c, 0, 0, 0);
}

__device__ __forceinline__ void gload16(const void* g, void* l) {
    __builtin_amdgcn_global_load_lds(
        (const __attribute__((address_space(1))) void*)g,
        (__attribute__((address_space(3))) void*)l, 16, 0, 0);
}

// ---------------- weight transpose + fp32->bf16 (0.125 fold on wq): wT[n][k] = w[k][n]
__global__ __launch_bounds__(256) void prep_kernel(const float* __restrict__ wq, const float* __restrict__ wk,
                                                   const float* __restrict__ wv, const float* __restrict__ wo,
                                                   uint16_t* __restrict__ tq, uint16_t* __restrict__ tk,
                                                   uint16_t* __restrict__ tv, uint16_t* __restrict__ to) {
    __shared__ uint16_t T[64][72];
    const int z = blockIdx.z;
    const int tid = threadIdx.x;
    const float* w = (z == 0) ? wq : (z == 1) ? wk : (z == 2) ? wv : wo;
    uint16_t* wT = (z == 0) ? tq : (z == 1) ? tk : (z == 2) ? tv : to;
    const float ws = (z == 0) ? 0.125f : 1.f;
    const int n0 = blockIdx.x * 64, k0 = blockIdx.y * 64;
    #pragma unroll
    for (int it = 0; it < 4; ++it) {
        int g = it * 256 + tid;
        int r = g >> 4, c = (g & 15) * 4;
        fl4 x = *(const fl4*)(w + (size_t)(k0 + r) * DMODEL + n0 + c);
        T[r][c + 0] = f2bf(x[0] * ws); T[r][c + 1] = f2bf(x[1] * ws);
        T[r][c + 2] = f2bf(x[2] * ws); T[r][c + 3] = f2bf(x[3] * ws);
    }
    __syncthreads();
    #pragma unroll
    for (int it = 0; it < 4; ++it) {
        int g = it * 256 + tid;
        int r = g >> 4, c = (g & 15) * 4;
        ushort4 o;
        o.x = T[c + 0][r]; o.y = T[c + 1][r]; o.z = T[c + 2][r]; o.w = T[c + 3][r];
        *(ushort4*)(wT + (size_t)(n0 + r) * DMODEL + k0 + c) = o;
    }
}

// ---------------- projection GEMM: T14 A reg-prefetch + B double-buffer (drain after MFMA);
// z=2 writes V transposed; grid (m=64, n=8, z=3); LDS 48KB -> 3 blocks/CU
__global__ __launch_bounds__(256)
void gemm_proj(const float* __restrict__ q, const float* __restrict__ k, const float* __restrict__ v,
               const uint16_t* __restrict__ B0, const uint16_t* __restrict__ B1, const uint16_t* __restrict__ B2,
               const float* __restrict__ b0, const float* __restrict__ b1, const float* __restrict__ b2,
               uint16_t* __restrict__ qh, uint16_t* __restrict__ kh, uint16_t* __restrict__ vT) {
    __shared__ uint16_t Alds[128 * 64];        // 16 KB
    __shared__ uint16_t Bbuf[2 * 128 * 64];    // 32 KB (also epilogue C-tile)
    const int z = blockIdx.z;
    const float* Af    = (z == 0) ? q : (z == 1) ? k : v;
    const uint16_t* Bt = (z == 0) ? B0 : (z == 1) ? B1 : B2;
    const float* bias  = (z == 0) ? b0 : (z == 1) ? b1 : b2;
    const float bs     = (z == 0) ? 0.125f : 1.f;
    const int m0 = blockIdx.x * 128, n0 = blockIdx.y * 128;
    const int tid = threadIdx.x, lane = tid & 63, wid = tid >> 6;
    const int wr = (wid >> 1) * 64, wc = (wid & 1) * 64;
    const int fr = lane & 15, fk = (lane >> 4) * 8, frow4 = (lane >> 4) * 4;

    fl4 acc[4][4];
    #pragma unroll
    for (int i = 0; i < 4; ++i)
        #pragma unroll
        for (int j = 0; j < 4; ++j) acc[i][j] = (fl4){0.f, 0.f, 0.f, 0.f};

    // prologue: pa = A(0); pack -> Alds; issue B(0) -> Bbuf[0]
    fl4 pa0[4], pa1[4];
    #pragma unroll
    for (int it = 0; it < 4; ++it) {
        const int g = it * 256 + tid;
        const int r = g >> 3, c = (g & 7) << 3;
        const float* p = Af + (size_t)(m0 + r) * DMODEL + c;
        pa0[it] = *(const fl4*)p; pa1[it] = *(const fl4*)(p + 4);
        *(sh8*)&Alds[r * 64 + c] = pack_bf8(pa0[it], pa1[it]);
        const int lofs = __builtin_amdgcn_readfirstlane((it * 256 + wid * 64) * 16);
        gload16(Bt + (size_t)(n0 + r) * DMODEL + c, (char*)Bbuf + lofs);
    }

    for (int kt = 0; kt < 16; ++kt) {
        if (kt > 0) {
            // pack pa (=A(kt)) -> Alds; MFMA(kt-1) reads completed at prior barrier-2
            #pragma unroll
            for (int it = 0; it < 4; ++it) {
                const int g = it * 256 + tid;
                const int r = g >> 3, c = (g & 7) << 3;
                *(sh8*)&Alds[r * 64 + c] = pack_bf8(pa0[it], pa1[it]);
            }
        }
        __syncthreads();    // barrier-1: Alds(kt) visible; Bbuf[kt&1] ready
        if (kt < 15) {
            // issue B(kt+1) into the other buffer + A(kt+1) reg loads; both fly under MFMA
            const int boff = ((kt + 1) & 1) * 128 * 64 * 2;   // byte offset of Bbuf half
            #pragma unroll
            for (int it = 0; it < 4; ++it) {
                const int g = it * 256 + tid;
                const int r = g >> 3, c = (g & 7) << 3;
                const int lofs = __builtin_amdgcn_readfirstlane((it * 256 + wid * 64) * 16);
                gload16(Bt + (size_t)(n0 + r) * DMODEL + (kt + 1) * 64 + c, (char*)Bbuf + boff + lofs);
                const float* p = Af + (size_t)(m0 + r) * DMODEL + (kt + 1) * 64 + c;
                pa0[it] = *(const fl4*)p; pa1[it] = *(const fl4*)(p + 4);
            }
        }
        const uint16_t* Bl = Bbuf + (kt & 1) * 128 * 64;
        #pragma unroll
        for (int ks = 0; ks < 2; ++ks) {
            sh8 a[4], bb[4];
            #pragma unroll
            for (int mi = 0; mi < 4; ++mi) a[mi] = *(const sh8*)&Alds[(wr + mi * 16 + fr) * 64 + ks * 32 + fk];
            #pragma unroll
            for (int ni = 0; ni < 4; ++ni) bb[ni] = *(const sh8*)&Bl[(wc + ni * 16 + fr) * 64 + ks * 32 + fk];
            #pragma unroll
            for (int mi = 0; mi < 4; ++mi)
                #pragma unroll
                for (int ni = 0; ni < 4; ++ni) acc[mi][ni] = mfma16(a[mi], bb[ni], acc[mi][ni]);
        }
        __syncthreads();    // barrier-2: drains B(kt+1)/pa AFTER MFMA; LDS reads complete
    }

    uint16_t* lds = Bbuf;   // 32 KB epilogue staging
    if (z < 2) {
        #pragma unroll
        for (int mi = 0; mi < 4; ++mi) {
            #pragma unroll
            for (int ni = 0; ni < 4; ++ni) {
                const int col = wc + ni * 16 + fr;
                const float bv = bias[n0 + col] * bs;
                #pragma unroll
                for (int i = 0; i < 4; ++i) {
                    const int row = wr + mi * 16 + frow4 + i;
                    lds[row * 128 + ((((col >> 3) ^ (row & 7)) << 3) | (col & 7))] = f2bf(acc[mi][ni][i] + bv);
                }
            }
        }
        __syncthreads();
        uint16_t* Cv = (z == 0) ? qh : kh;
        #pragma unroll
        for (int it = 0; it < 8; ++it) {
            const int ch = it * 256 + tid;
            const int row = ch >> 4, cc = ch & 15;
            sh8 vv = *(sh8*)&lds[row * 128 + ((cc ^ (row & 7)) << 3)];
            *(sh8*)(Cv + (size_t)(m0 + row) * DMODEL + n0 + cc * 8) = vv;
        }
    } else {
        #pragma unroll
        for (int mi = 0; mi < 4; ++mi) {
            #pragma unroll
            for (int ni = 0; ni < 4; ++ni) {
                const int col = wc + ni * 16 + fr;
                const float bv = bias[n0 + col];
                #pragma unroll
                for (int i = 0; i < 4; ++i) {
                    const int row = wr + mi * 16 + frow4 + i;
                    lds[col * 128 + ((((row >> 3) ^ (col & 7)) << 3) | (row & 7))] = f2bf(acc[mi][ni][i] + bv);
                }
            }
        }
        __syncthreads();
        const int b = m0 >> 10, l0 = m0 & 1023;
        #pragma unroll
        for (int it = 0; it < 8; ++it) {
            const int ch = it * 256 + tid;
            const int col = ch >> 4, rc = ch & 15;
            sh8 vv = *(sh8*)&lds[col * 128 + ((rc ^ (col & 7)) << 3)];
            *(sh8*)(vT + (size_t)(b * 1024 + n0 + col) * SEQ + l0 + rc * 8) = vv;
        }
    }
}

// ---------------- out-proj GEMM: full A+B double-buffer, SINGLE barrier/tile; fp32 out + residual
// grid (64, 8); LDS 64KB -> 2 blocks/CU
__global__ __launch_bounds__(256)
void gemm_out(const uint16_t* __restrict__ Ab, const uint16_t* __restrict__ Bt,
              const float* __restrict__ bias, const float* __restrict__ resid,
              float* __restrict__ Cv) {
    __shared__ uint16_t Ab2[2 * 128 * 64];    // 32 KB (also epilogue flds)
    __shared__ uint16_t Bb2[2 * 128 * 64];    // 32 KB
    const int m0 = blockIdx.x * 128, n0 = blockIdx.y * 128;
    const int tid = threadIdx.x, lane = tid & 63, wid = tid >> 6;
    const int wr = (wid >> 1) * 64, wc = (wid & 1) * 64;
    const int fr = lane & 15, fk = (lane >> 4) * 8, frow4 = (lane >> 4) * 4;

    fl4 acc[4][4];
    #pragma unroll
    for (int i = 0; i < 4; ++i)
        #pragma unroll
        for (int j = 0; j < 4; ++j) acc[i][j] = (fl4){0.f, 0.f, 0.f, 0.f};

    // prologue: issue A(0),B(0) -> buf0
    #pragma unroll
    for (int it = 0; it < 4; ++it) {
        const int g = it * 256 + tid;
        const int r = g >> 3, c = (g & 7) << 3;
        const int lofs = __builtin_amdgcn_readfirstlane((it * 256 + wid * 64) * 16);
        gload16(Ab + (size_t)(m0 + r) * DMODEL + c, (char*)Ab2 + lofs);
        gload16(Bt + (size_t)(n0 + r) * DMODEL + c, (char*)Bb2 + lofs);
    }

    for (int kt = 0; kt < 16; ++kt) {
        __syncthreads();    // drains gloads for buf[kt&1]; also orders vs MFMA(kt-1) reads of buf[(kt+1)&1]
        if (kt < 15) {
            const int boff = ((kt + 1) & 1) * 128 * 64 * 2;
            #pragma unroll
            for (int it = 0; it < 4; ++it) {
                const int g = it * 256 + tid;
                const int r = g >> 3, c = (g & 7) << 3;
                const int lofs = __builtin_amdgcn_readfirstlane((it * 256 + wid * 64) * 16);
                gload16(Ab + (size_t)(m0 + r) * DMODEL + (kt + 1) * 64 + c, (char*)Ab2 + boff + lofs);
                gload16(Bt + (size_t)(n0 + r) * DMODEL + (kt + 1) * 64 + c, (char*)Bb2 + boff + lofs);
            }
        }
        const uint16_t* Al = Ab2 + (kt & 1) * 128 * 64;
        const uint16_t* Bl = Bb2 + (kt & 1) * 128 * 64;
        #pragma unroll
        for (int ks = 0; ks < 2; ++ks) {
            sh8 a[4], bb[4];
            #pragma unroll
            for (int mi = 0; mi < 4; ++mi) a[mi] = *(const sh8*)&Al[(wr + mi * 16 + fr) * 64 + ks * 32 + fk];
            #pragma unroll
            for (int ni = 0; ni < 4; ++ni) bb[ni] = *(const sh8*)&Bl[(wc + ni * 16 + fr) * 64 + ks * 32 + fk];
            #pragma unroll
            for (int mi = 0; mi < 4; ++mi)
                #pragma unroll
                for (int ni = 0; ni < 4; ++ni) acc[mi][ni] = mfma16(a[mi], bb[ni], acc[mi][ni]);
        }
    }
    __syncthreads();        // all LDS reads done before epilogue reuse

    // fp32 (+resid): two 64-col halves through Ab2's 32KB
    float* flds = (float*)Ab2;
    #pragma unroll
    for (int h2 = 0; h2 < 2; ++h2) {
        if (h2) __syncthreads();
        if (wc == h2 * 64) {
            #pragma unroll
            for (int ni = 0; ni < 4; ++ni) {
                const int col = wc + ni * 16 + fr;
                const int ch = col - h2 * 64;
                const float bv = bias[n0 + col];
                #pragma unroll
                for (int mi = 0; mi < 4; ++mi) {
                    #pragma unroll
                    for (int i = 0; i < 4; ++i) {
                        const int row = wr + mi * 16 + frow4 + i;
                        float val = acc[mi][ni][i] + bv;
                        val += resid[(size_t)(m0 + row) * DMODEL + n0 + col];
                        flds[row * 64 + ((((ch >> 2) ^ (row & 7)) << 2) | (ch & 3))] = val;
                    }
                }
            }
        }
        __syncthreads();
        #pragma unroll
        for (int it = 0; it < 8; ++it) {
            const int ck = it * 256 + tid;
            const int row = ck >> 4, cc = ck & 15;
            fl4 vv = *(fl4*)&flds[row * 64 + ((cc ^ (row & 7)) << 2)];
            *(fl4*)(Cv + (size_t)(m0 + row) * DMODEL + n0 + h2 * 64 + cc * 4) = vv;
        }
    }
}

// ---------------- attention: block = (b, h, 16 q-rows); S bf16[16][1024] swizzled (r12-measured structure)
__global__ __launch_bounds__(256)
void attn_kernel(const uint16_t* __restrict__ qh, const uint16_t* __restrict__ kh,
                 const uint16_t* __restrict__ vT, const uint8_t* __restrict__ mask,
                 float* __restrict__ attn, uint16_t* __restrict__ ctx) {
    __shared__ uint16_t S[16 * 1024];       // 32 KB
    __shared__ float rinv[16];
    const int b = blockIdx.x, h = blockIdx.y, q0 = blockIdx.z * 16;
    const int tid = threadIdx.x, lane = tid & 63, wid = tid >> 6;
    const int fr = lane & 15, fk = (lane >> 4) * 8, frow4 = (lane >> 4) * 4;

    sh8 Aq[2];
    #pragma unroll
    for (int ks = 0; ks < 2; ++ks)
        Aq[ks] = *(const sh8*)(qh + (size_t)(b * SEQ + q0 + fr) * DMODEL + h * 64 + ks * 32 + fk);

    // phase 1: S = bf16(QK^T)  (qh pre-scaled by 1/sqrt(dk))
    for (int t8 = 0; t8 < 8; ++t8) {
        const int kv0 = (t8 * 4 + wid) * 32;
        sh8 Bk[2][2];
        #pragma unroll
        for (int ni = 0; ni < 2; ++ni)
            #pragma unroll
            for (int ks = 0; ks < 2; ++ks)
                Bk[ni][ks] = *(const sh8*)(kh + (size_t)(b * SEQ + kv0 + ni * 16 + fr) * DMODEL + h * 64 + ks * 32 + fk);
        fl4 sa[2];
        #pragma unroll
        for (int ni = 0; ni < 2; ++ni) sa[ni] = (fl4){0.f, 0.f, 0.f, 0.f};
        #pragma unroll
        for (int ni = 0; ni < 2; ++ni)
            #pragma unroll
            for (int ks = 0; ks < 2; ++ks) sa[ni] = mfma16(Aq[ks], Bk[ni][ks], sa[ni]);
        #pragma unroll
        for (int ni = 0; ni < 2; ++ni)
            #pragma unroll
            for (int i = 0; i < 4; ++i) {
                const int row = frow4 + i, col = kv0 + ni * 16 + fr;
                S[row * 1024 + ((((col >> 3) ^ (row & 15)) << 3) | (col & 7))] = f2bf(sa[ni][i]);
            }
    }
    __syncthreads();

    // phase 2: masked softmax in regs (zero-mask fast path); exp (unnormalized, bf16) -> S; rinv per row
    {
        const int r = tid >> 4, j = tid & 15;
        const int rbase = r * 1024;
        const uint8_t* mbase = mask + (size_t)(b * SEQ + q0 + r) * SEQ;
        sh8 x[8];
        uint2 mw[8];
        #pragma unroll
        for (int c4 = 0; c4 < 8; ++c4) {
            const int cc = c4 * 16 + j;
            x[c4] = *(sh8*)&S[rbase + ((cc ^ r) << 3)];
            mw[c4] = *(const uint2*)(mbase + cc * 8);
        }
        uint32_t anym = 0;
        #pragma unroll
        for (int c4 = 0; c4 < 8; ++c4) anym |= (mw[c4].x | mw[c4].y);
        float mx = -1e30f;
        if (anym == 0) {
            #pragma unroll
            for (int c4 = 0; c4 < 8; ++c4)
                #pragma unroll
                for (int t = 0; t < 8; ++t) mx = fmaxf(mx, b2f((uint16_t)x[c4][t]));
        } else {
            #pragma unroll
            for (int c4 = 0; c4 < 8; ++c4) {
                float f[8];
                #pragma unroll
                for (int t = 0; t < 4; ++t)
                    f[t] = ((mw[c4].x >> (t * 8)) & 0xFF) ? -1e9f : b2f((uint16_t)x[c4][t]);
                #pragma unroll
                for (int t = 0; t < 4; ++t)
                    f[4 + t] = ((mw[c4].y >> (t * 8)) & 0xFF) ? -1e9f : b2f((uint16_t)x[c4][4 + t]);
                union { uint32_t w[4]; sh8 v; } pk;
                pk.w[0] = cvtpk(f[0], f[1]); pk.w[1] = cvtpk(f[2], f[3]);
                pk.w[2] = cvtpk(f[4], f[5]); pk.w[3] = cvtpk(f[6], f[7]);
                x[c4] = pk.v;
                #pragma unroll
                for (int t = 0; t < 8; ++t) mx = fmaxf(mx, f[t]);
            }
        }
        #pragma unroll
        for (int d = 1; d < 16; d <<= 1) mx = fmaxf(mx, __shfl_xor(mx, d));
        float sum = 0.f;
        #pragma unroll
        for (int c4 = 0; c4 < 8; ++c4) {
            const int cc = c4 * 16 + j;
            float e[8];
            #pragma unroll
            for (int t = 0; t < 8; ++t) e[t] = __expf(b2f((uint16_t)x[c4][t]) - mx);
            union { uint32_t w[4]; sh8 v; } pk;
            pk.w[0] = cvtpk(e[0], e[1]); pk.w[1] = cvtpk(e[2], e[3]);
            pk.w[2] = cvtpk(e[4], e[5]); pk.w[3] = cvtpk(e[6], e[7]);
            *(sh8*)&S[rbase + ((cc ^ r) << 3)] = pk.v;
            sum += e[0] + e[1] + e[2] + e[3] + e[4] + e[5] + e[6] + e[7];
        }
        #pragma unroll
        for (int d = 1; d < 16; d <<= 1) sum += __shfl_xor(sum, d);
        if (j == 0) rinv[r] = 1.f / sum;
    }
    __syncthreads();

    // phase 3a: attn global write first, block-linear coalesced, NT; drains under PV below
    {
        float* ab = attn + ((size_t)((h * BATCH + b) * SEQ + q0)) * SEQ;
        #pragma unroll
        for (int it = 0; it < 16; ++it) {
            const int ch = it * 256 + tid;
            const int row = ch >> 8, oc = ch & 255;
            const int cc = oc >> 1, half = oc & 1;
            const ushort4 p = *(const ushort4*)&S[row * 1024 + ((cc ^ row) << 3) + half * 4];
            const float ri = rinv[row];
            fl4 o;
            o[0] = b2f(p.x) * ri; o[1] = b2f(p.y) * ri;
            o[2] = b2f(p.z) * ri; o[3] = b2f(p.w) * ri;
            __builtin_nontemporal_store(o, (fl4*)(ab + (size_t)ch * 4));
        }
    }

    // phase 3b: ctx = (P_unnorm V) * rinv ; wave wid owns d-block [wid*16, wid*16+16)
    fl4 acc0 = (fl4){0.f, 0.f, 0.f, 0.f}, acc1 = (fl4){0.f, 0.f, 0.f, 0.f};
    const uint16_t* vbase = vT + (size_t)((b * NHEAD + h) * 64 + wid * 16) * SEQ;
    #pragma unroll 4
    for (int ks2 = 0; ks2 < 32; ++ks2) {
        const int kv = ks2 * 32;
        sh8 Ap = *(const sh8*)&S[fr * 1024 + ((((kv + fk) >> 3) ^ fr) << 3)];
        sh8 Bv = *(const sh8*)(vbase + (size_t)fr * SEQ + kv + fk);
        if (ks2 & 1) acc1 = mfma16(Ap, Bv, acc1);
        else         acc0 = mfma16(Ap, Bv, acc0);
    }
    __syncthreads();

    // phase 4: ctx via 2 KB LDS bounce -> coalesced 8B/lane stores
    {
        uint16_t* Sc = S;
        #pragma unroll
        for (int i = 0; i < 4; ++i) {
            const int qr = frow4 + i;
            Sc[qr * 64 + wid * 16 + fr] = f2bf((acc0[i] + acc1[i]) * rinv[qr]);
        }
        __syncthreads();
        const int row = tid >> 4, c4 = (tid & 15) * 4;
        ushort4 vv = *(ushort4*)&Sc[row * 64 + c4];
        *(ushort4*)(ctx + (size_t)(b * SEQ + q0 + row) * DMODEL + h * 64 + c4) = vv;
    }
}

// ---------------- LayerNorm (in-place): one block per row
__global__ __launch_bounds__(256)
void ln_kernel(const float* __restrict__ raw, const float* __restrict__ gamma,
               const float* __restrict__ beta, float* __restrict__ out) {
    const int row = blockIdx.x;
    const int tid = threadIdx.x;
    const float* x = raw + (size_t)row * DMODEL;
    fl4 xv = *(const fl4*)(x + tid * 4);
    float s  = xv[0] + xv[1] + xv[2] + xv[3];
    float ss = xv[0] * xv[0] + xv[1] * xv[1] + xv[2] * xv[2] + xv[3] * xv[3];
    #pragma unroll
    for (int d = 1; d < 64; d <<= 1) { s += __shfl_xor(s, d); ss += __shfl_xor(ss, d); }
    __shared__ float sb[4], ssb[4];
    if ((tid & 63) == 0) { sb[tid >> 6] = s; ssb[tid >> 6] = ss; }
    __syncthreads();
    s  = sb[0] + sb[1] + sb[2] + sb[3];
    ss = ssb[0] + ssb[1] + ssb[2] + ssb[3];
    const float mu  = s * (1.f / 1024.f);
    const float var = ss * (1.f / 1024.f) - mu * mu;
    const float rstd = rsqrtf(var + 1e-5f);
    fl4 g  = *(const fl4*)(gamma + tid * 4);
    fl4 be = *(const fl4*)(beta + tid * 4);
    fl4 o;
    #pragma unroll
    for (int j = 0; j < 4; ++j) o[j] = (xv[j] - mu) * rstd * g[j] + be[j];
    *(fl4*)(out + (size_t)row * DMODEL + tid * 4) = o;
}

extern "C" void kernel_launch(void* const* d_in, const int* in_sizes, int n_in,
                              void* d_out, int out_size, void* d_ws, size_t ws_size,
                              hipStream_t stream) {
    (void)in_sizes; (void)n_in; (void)out_size; (void)ws_size;
    const float* q     = (const float*)d_in[0];
    const float* k     = (const float*)d_in[1];
    const float* v     = (const float*)d_in[2];
    const uint8_t* mask = (const uint8_t*)d_in[3];
    const float* wq = (const float*)d_in[4];
    const float* bq = (const float*)d_in[5];
    const float* wk = (const float*)d_in[6];
    const float* bk = (const float*)d_in[7];
    const float* wv = (const float*)d_in[8];
    const float* bv = (const float*)d_in[9];
    const float* wo = (const float*)d_in[10];
    const float* bo = (const float*)d_in[11];
    const float* gamma = (const float*)d_in[12];
    const float* beta  = (const float*)d_in[13];

    float* out  = (float*)d_out;
    float* attn = out + (size_t)BATCH * SEQ * DMODEL;

    char* ws = (char*)d_ws;
    uint16_t* qh   = (uint16_t*)(ws);
    uint16_t* kh   = (uint16_t*)(ws + ((size_t)16 << 20));
    uint16_t* vT   = (uint16_t*)(ws + ((size_t)32 << 20));
    uint16_t* ctx  = (uint16_t*)(ws + ((size_t)48 << 20));
    uint16_t* wqT  = (uint16_t*)(ws + ((size_t)64 << 20));
    uint16_t* wkT  = (uint16_t*)(ws + ((size_t)66 << 20));
    uint16_t* wvT  = (uint16_t*)(ws + ((size_t)68 << 20));
    uint16_t* woT  = (uint16_t*)(ws + ((size_t)70 << 20));

    dim3 tb(256);
    prep_kernel<<<dim3(16, 16, 4), tb, 0, stream>>>(wq, wk, wv, wo, wqT, wkT, wvT, woT);

    gemm_proj<<<dim3(64, 8, 3), tb, 0, stream>>>(q, k, v, wqT, wkT, wvT,
                                                 bq, bk, bv, qh, kh, vT);

    attn_kernel<<<dim3(BATCH, NHEAD, 64), tb, 0, stream>>>(qh, kh, vT, mask, attn, ctx);

    gemm_out<<<dim3(64, 8), tb, 0, stream>>>(ctx, woT, bo, q, out);

    ln_kernel<<<BATCH * SEQ, tb, 0, stream>>>(out, gamma, beta, out);
}

// Round 14
// 411.996 us; speedup vs baseline: 1.0337x; 1.0337x over previous
//
#include <hip/hip_runtime.h>
#include <stdint.h>

static constexpr int BATCH  = 8;
static constexpr int SEQ    = 1024;
static constexpr int DMODEL = 1024;
static constexpr int NHEAD  = 16;

typedef __attribute__((ext_vector_type(8))) short sh8;
typedef __attribute__((ext_vector_type(4))) float fl4;

__device__ __forceinline__ uint16_t f2bf(float f) {
    union { float f; uint32_t u; } a; a.f = f;
    uint32_t r = a.u + 0x7FFFu + ((a.u >> 16) & 1u);
    return (uint16_t)(r >> 16);
}

__device__ __forceinline__ float b2f(uint16_t u) {
    union { uint32_t u; float f; } a; a.u = ((uint32_t)u) << 16; return a.f;
}

// HW packed fp32->bf16 (RNE)
__device__ __forceinline__ uint32_t cvtpk(float lo, float hi) {
    uint32_t r;
    asm("v_cvt_pk_bf16_f32 %0, %1, %2" : "=v"(r) : "v"(lo), "v"(hi));
    return r;
}

__device__ __forceinline__ sh8 pack_bf8(fl4 x0, fl4 x1) {
    union { uint32_t w[4]; sh8 v; } pk;
    pk.w[0] = cvtpk(x0[0], x0[1]); pk.w[1] = cvtpk(x0[2], x0[3]);
    pk.w[2] = cvtpk(x1[0], x1[1]); pk.w[3] = cvtpk(x1[2], x1[3]);
    return pk.v;
}

__device__ __forceinline__ fl4 mfma16(sh8 a, sh8 b, fl4 c) {
    return __builtin_amdgcn_mfma_f32_16x16x32_bf16(a, b, c, 0, 0, 0);
}

__device__ __forceinline__ void gload16(const void* g, void* l) {
    __builtin_amdgcn_global_load_lds(
        (const __attribute__((address_space(1))) void*)g,
        (__attribute__((address_space(3))) void*)l, 16, 0, 0);
}

// ---------------- weight transpose + fp32->bf16 (0.125 fold on wq): wT[n][k] = w[k][n]
__global__ __launch_bounds__(256) void prep_kernel(const float* __restrict__ wq, const float* __restrict__ wk,
                                                   const float* __restrict__ wv, const float* __restrict__ wo,
                                                   uint16_t* __restrict__ tq, uint16_t* __restrict__ tk,
                                                   uint16_t* __restrict__ tv, uint16_t* __restrict__ to) {
    __shared__ uint16_t T[64][72];
    const int z = blockIdx.z;
    const int tid = threadIdx.x;
    const float* w = (z == 0) ? wq : (z == 1) ? wk : (z == 2) ? wv : wo;
    uint16_t* wT = (z == 0) ? tq : (z == 1) ? tk : (z == 2) ? tv : to;
    const float ws = (z == 0) ? 0.125f : 1.f;
    const int n0 = blockIdx.x * 64, k0 = blockIdx.y * 64;
    #pragma unroll
    for (int it = 0; it < 4; ++it) {
        int g = it * 256 + tid;
        int r = g >> 4, c = (g & 15) * 4;
        fl4 x = *(const fl4*)(w + (size_t)(k0 + r) * DMODEL + n0 + c);
        T[r][c + 0] = f2bf(x[0] * ws); T[r][c + 1] = f2bf(x[1] * ws);
        T[r][c + 2] = f2bf(x[2] * ws); T[r][c + 3] = f2bf(x[3] * ws);
    }
    __syncthreads();
    #pragma unroll
    for (int it = 0; it < 4; ++it) {
        int g = it * 256 + tid;
        int r = g >> 4, c = (g & 15) * 4;
        ushort4 o;
        o.x = T[c + 0][r]; o.y = T[c + 1][r]; o.z = T[c + 2][r]; o.w = T[c + 3][r];
        *(ushort4*)(wT + (size_t)(n0 + r) * DMODEL + k0 + c) = o;
    }
}

// ---------------- projection GEMM: fused fp32->bf16 A-staging with T14 register prefetch;
// z=2 writes V transposed; grid (m=64, n=8, z=3)
__global__ __launch_bounds__(256)
void gemm_proj(const float* __restrict__ q, const float* __restrict__ k, const float* __restrict__ v,
               const uint16_t* __restrict__ B0, const uint16_t* __restrict__ B1, const uint16_t* __restrict__ B2,
               const float* __restrict__ b0, const float* __restrict__ b1, const float* __restrict__ b2,
               uint16_t* __restrict__ qh, uint16_t* __restrict__ kh, uint16_t* __restrict__ vT) {
    __shared__ uint16_t lds[128 * 128];     // 32 KB: A|B staging, then epilogue C-tile
    uint16_t* Alds = lds;
    uint16_t* Blds = lds + 128 * 64;
    const int z = blockIdx.z;
    const float* Af    = (z == 0) ? q : (z == 1) ? k : v;
    const uint16_t* Bt = (z == 0) ? B0 : (z == 1) ? B1 : B2;
    const float* bias  = (z == 0) ? b0 : (z == 1) ? b1 : b2;
    const float bs     = (z == 0) ? 0.125f : 1.f;
    const int m0 = blockIdx.x * 128, n0 = blockIdx.y * 128;
    const int tid = threadIdx.x, lane = tid & 63, wid = tid >> 6;
    const int wr = (wid >> 1) * 64, wc = (wid & 1) * 64;
    const int fr = lane & 15, fk = (lane >> 4) * 8, frow4 = (lane >> 4) * 4;

    fl4 acc[4][4];
    #pragma unroll
    for (int i = 0; i < 4; ++i)
        #pragma unroll
        for (int j = 0; j < 4; ++j) acc[i][j] = (fl4){0.f, 0.f, 0.f, 0.f};

    // T14 prologue: preload A K-tile 0 into registers
    fl4 pa0[4], pa1[4];
    #pragma unroll
    for (int it = 0; it < 4; ++it) {
        const int g = it * 256 + tid;
        const int r = g >> 3, c = (g & 7) << 3;
        const float* p = Af + (size_t)(m0 + r) * DMODEL + c;
        pa0[it] = *(const fl4*)p; pa1[it] = *(const fl4*)(p + 4);
    }

    for (int kt = 0; kt < 16; ++kt) {
        const int kb = kt * 64;
        #pragma unroll
        for (int it = 0; it < 4; ++it) {
            const int g = it * 256 + tid;
            const int r = g >> 3, c = (g & 7) << 3;
            // A: cvt + ds_write from prefetched regs (no load on critical path)
            *(sh8*)&Alds[r * 64 + c] = pack_bf8(pa0[it], pa1[it]);
            // B: async global->LDS
            const int lofs = __builtin_amdgcn_readfirstlane((it * 256 + wid * 64) * 16);
            gload16(Bt + (size_t)(n0 + r) * DMODEL + kb + c, (char*)Blds + lofs);
        }
        __syncthreads();
        // issue next A-tile loads; latency hides under the MFMA cluster below
        if (kt < 15) {
            #pragma unroll
            for (int it = 0; it < 4; ++it) {
                const int g = it * 256 + tid;
                const int r = g >> 3, c = (g & 7) << 3;
                const float* p = Af + (size_t)(m0 + r) * DMODEL + kb + 64 + c;
                pa0[it] = *(const fl4*)p; pa1[it] = *(const fl4*)(p + 4);
            }
        }
        #pragma unroll
        for (int ks = 0; ks < 2; ++ks) {
            sh8 a[4], bb[4];
            #pragma unroll
            for (int mi = 0; mi < 4; ++mi) a[mi] = *(const sh8*)&Alds[(wr + mi * 16 + fr) * 64 + ks * 32 + fk];
            #pragma unroll
            for (int ni = 0; ni < 4; ++ni) bb[ni] = *(const sh8*)&Blds[(wc + ni * 16 + fr) * 64 + ks * 32 + fk];
            #pragma unroll
            for (int mi = 0; mi < 4; ++mi)
                #pragma unroll
                for (int ni = 0; ni < 4; ++ni) acc[mi][ni] = mfma16(a[mi], bb[ni], acc[mi][ni]);
        }
        __syncthreads();
    }

    if (z < 2) {
        // normal layout: stage 128x128 bf16 tile (chunk-xor swizzle), drain coalesced
        #pragma unroll
        for (int mi = 0; mi < 4; ++mi) {
            #pragma unroll
            for (int ni = 0; ni < 4; ++ni) {
                const int col = wc + ni * 16 + fr;
                const float bv = bias[n0 + col] * bs;
                #pragma unroll
                for (int i = 0; i < 4; ++i) {
                    const int row = wr + mi * 16 + frow4 + i;
                    lds[row * 128 + ((((col >> 3) ^ (row & 7)) << 3) | (col & 7))] = f2bf(acc[mi][ni][i] + bv);
                }
            }
        }
        __syncthreads();
        uint16_t* Cv = (z == 0) ? qh : kh;
        #pragma unroll
        for (int it = 0; it < 8; ++it) {
            const int ch = it * 256 + tid;
            const int row = ch >> 4, cc = ch & 15;
            sh8 vv = *(sh8*)&lds[row * 128 + ((cc ^ (row & 7)) << 3)];
            *(sh8*)(Cv + (size_t)(m0 + row) * DMODEL + n0 + cc * 8) = vv;
        }
    } else {
        // transposed: stage tile as ldsT[col][row] (row-chunk xor swizzle), write to vT[b*1024+hd][l]
        #pragma unroll
        for (int mi = 0; mi < 4; ++mi) {
            #pragma unroll
            for (int ni = 0; ni < 4; ++ni) {
                const int col = wc + ni * 16 + fr;
                const float bv = bias[n0 + col];
                #pragma unroll
                for (int i = 0; i < 4; ++i) {
                    const int row = wr + mi * 16 + frow4 + i;
                    lds[col * 128 + ((((row >> 3) ^ (col & 7)) << 3) | (row & 7))] = f2bf(acc[mi][ni][i] + bv);
                }
            }
        }
        __syncthreads();
        const int b = m0 >> 10, l0 = m0 & 1023;
        #pragma unroll
        for (int it = 0; it < 8; ++it) {
            const int ch = it * 256 + tid;
            const int col = ch >> 4, rc = ch & 15;
            sh8 vv = *(sh8*)&lds[col * 128 + ((rc ^ (col & 7)) << 3)];
            *(sh8*)(vT + (size_t)(b * 1024 + n0 + col) * SEQ + l0 + rc * 8) = vv;
        }
    }
}

// ---------------- out-proj GEMM: bf16 A (ctx) via gload_lds, fp32 out + residual; grid (64, 8)
__global__ __launch_bounds__(256)
void gemm_out(const uint16_t* __restrict__ Ab, const uint16_t* __restrict__ Bt,
              const float* __restrict__ bias, const float* __restrict__ resid,
              float* __restrict__ Cv) {
    __shared__ uint16_t lds[128 * 128];
    uint16_t* Alds = lds;
    uint16_t* Blds = lds + 128 * 64;
    const int m0 = blockIdx.x * 128, n0 = blockIdx.y * 128;
    const int tid = threadIdx.x, lane = tid & 63, wid = tid >> 6;
    const int wr = (wid >> 1) * 64, wc = (wid & 1) * 64;
    const int fr = lane & 15, fk = (lane >> 4) * 8, frow4 = (lane >> 4) * 4;

    fl4 acc[4][4];
    #pragma unroll
    for (int i = 0; i < 4; ++i)
        #pragma unroll
        for (int j = 0; j < 4; ++j) acc[i][j] = (fl4){0.f, 0.f, 0.f, 0.f};

    for (int kt = 0; kt < 16; ++kt) {
        const int kb = kt * 64;
        #pragma unroll
        for (int it = 0; it < 4; ++it) {
            const int g = it * 256 + tid;
            const int r = g >> 3, c = (g & 7) << 3;
            const int lofs = __builtin_amdgcn_readfirstlane((it * 256 + wid * 64) * 16);
            gload16(Ab + (size_t)(m0 + r) * DMODEL + kb + c, (char*)Alds + lofs);
            gload16(Bt + (size_t)(n0 + r) * DMODEL + kb + c, (char*)Blds + lofs);
        }
        __syncthreads();
        #pragma unroll
        for (int ks = 0; ks < 2; ++ks) {
            sh8 a[4], bb[4];
            #pragma unroll
            for (int mi = 0; mi < 4; ++mi) a[mi] = *(const sh8*)&Alds[(wr + mi * 16 + fr) * 64 + ks * 32 + fk];
            #pragma unroll
            for (int ni = 0; ni < 4; ++ni) bb[ni] = *(const sh8*)&Blds[(wc + ni * 16 + fr) * 64 + ks * 32 + fk];
            #pragma unroll
            for (int mi = 0; mi < 4; ++mi)
                #pragma unroll
                for (int ni = 0; ni < 4; ++ni) acc[mi][ni] = mfma16(a[mi], bb[ni], acc[mi][ni]);
        }
        __syncthreads();
    }

    // fp32 (+resid): two 64-col halves through 32 KB lds
    float* flds = (float*)lds;
    #pragma unroll
    for (int h2 = 0; h2 < 2; ++h2) {
        if (h2) __syncthreads();
        if (wc == h2 * 64) {
            #pragma unroll
            for (int ni = 0; ni < 4; ++ni) {
                const int col = wc + ni * 16 + fr;
                const int ch = col - h2 * 64;
                const float bv = bias[n0 + col];
                #pragma unroll
                for (int mi = 0; mi < 4; ++mi) {
                    #pragma unroll
                    for (int i = 0; i < 4; ++i) {
                        const int row = wr + mi * 16 + frow4 + i;
                        float val = acc[mi][ni][i] + bv;
                        val += resid[(size_t)(m0 + row) * DMODEL + n0 + col];
                        flds[row * 64 + ((((ch >> 2) ^ (row & 7)) << 2) | (ch & 3))] = val;
                    }
                }
            }
        }
        __syncthreads();
        #pragma unroll
        for (int it = 0; it < 8; ++it) {
            const int ck = it * 256 + tid;
            const int row = ck >> 4, cc = ck & 15;
            fl4 vv = *(fl4*)&flds[row * 64 + ((cc ^ (row & 7)) << 2)];
            *(fl4*)(Cv + (size_t)(m0 + row) * DMODEL + n0 + h2 * 64 + cc * 4) = vv;
        }
    }
}

// ---------------- attention: block = (b, h, 16 q-rows); S bf16[16][1024] swizzled
__global__ __launch_bounds__(256)
void attn_kernel(const uint16_t* __restrict__ qh, const uint16_t* __restrict__ kh,
                 const uint16_t* __restrict__ vT, const uint8_t* __restrict__ mask,
                 float* __restrict__ attn, uint16_t* __restrict__ ctx) {
    __shared__ uint16_t S[16 * 1024];       // 32 KB
    __shared__ float rinv[16];
    const int b = blockIdx.x, h = blockIdx.y, q0 = blockIdx.z * 16;
    const int tid = threadIdx.x, lane = tid & 63, wid = tid >> 6;
    const int fr = lane & 15, fk = (lane >> 4) * 8, frow4 = (lane >> 4) * 4;

    sh8 Aq[2];
    #pragma unroll
    for (int ks = 0; ks < 2; ++ks)
        Aq[ks] = *(const sh8*)(qh + (size_t)(b * SEQ + q0 + fr) * DMODEL + h * 64 + ks * 32 + fk);

    // phase 1: S = bf16(QK^T)  (qh pre-scaled by 1/sqrt(dk))
    for (int t8 = 0; t8 < 8; ++t8) {
        const int kv0 = (t8 * 4 + wid) * 32;
        sh8 Bk[2][2];
        #pragma unroll
        for (int ni = 0; ni < 2; ++ni)
            #pragma unroll
            for (int ks = 0; ks < 2; ++ks)
                Bk[ni][ks] = *(const sh8*)(kh + (size_t)(b * SEQ + kv0 + ni * 16 + fr) * DMODEL + h * 64 + ks * 32 + fk);
        fl4 sa[2];
        #pragma unroll
        for (int ni = 0; ni < 2; ++ni) sa[ni] = (fl4){0.f, 0.f, 0.f, 0.f};
        #pragma unroll
        for (int ni = 0; ni < 2; ++ni)
            #pragma unroll
            for (int ks = 0; ks < 2; ++ks) sa[ni] = mfma16(Aq[ks], Bk[ni][ks], sa[ni]);
        #pragma unroll
        for (int ni = 0; ni < 2; ++ni)
            #pragma unroll
            for (int i = 0; i < 4; ++i) {
                const int row = frow4 + i, col = kv0 + ni * 16 + fr;
                S[row * 1024 + ((((col >> 3) ^ (row & 15)) << 3) | (col & 7))] = f2bf(sa[ni][i]);
            }
    }
    __syncthreads();

    // phase 2: masked softmax in regs (zero-mask fast path); exp (unnormalized, bf16) -> S; rinv per row
    {
        const int r = tid >> 4, j = tid & 15;
        const int rbase = r * 1024;
        const uint8_t* mbase = mask + (size_t)(b * SEQ + q0 + r) * SEQ;
        sh8 x[8];
        uint2 mw[8];
        #pragma unroll
        for (int c4 = 0; c4 < 8; ++c4) {
            const int cc = c4 * 16 + j;
            x[c4] = *(sh8*)&S[rbase + ((cc ^ r) << 3)];
            mw[c4] = *(const uint2*)(mbase + cc * 8);
        }
        uint32_t anym = 0;
        #pragma unroll
        for (int c4 = 0; c4 < 8; ++c4) anym |= (mw[c4].x | mw[c4].y);
        float mx = -1e30f;
        if (anym == 0) {
            #pragma unroll
            for (int c4 = 0; c4 < 8; ++c4)
                #pragma unroll
                for (int t = 0; t < 8; ++t) mx = fmaxf(mx, b2f((uint16_t)x[c4][t]));
        } else {
            #pragma unroll
            for (int c4 = 0; c4 < 8; ++c4) {
                float f[8];
                #pragma unroll
                for (int t = 0; t < 4; ++t)
                    f[t] = ((mw[c4].x >> (t * 8)) & 0xFF) ? -1e9f : b2f((uint16_t)x[c4][t]);
                #pragma unroll
                for (int t = 0; t < 4; ++t)
                    f[4 + t] = ((mw[c4].y >> (t * 8)) & 0xFF) ? -1e9f : b2f((uint16_t)x[c4][4 + t]);
                union { uint32_t w[4]; sh8 v; } pk;
                pk.w[0] = cvtpk(f[0], f[1]); pk.w[1] = cvtpk(f[2], f[3]);
                pk.w[2] = cvtpk(f[4], f[5]); pk.w[3] = cvtpk(f[6], f[7]);
                x[c4] = pk.v;
                #pragma unroll
                for (int t = 0; t < 8; ++t) mx = fmaxf(mx, f[t]);
            }
        }
        #pragma unroll
        for (int d = 1; d < 16; d <<= 1) mx = fmaxf(mx, __shfl_xor(mx, d));
        float sum = 0.f;
        #pragma unroll
        for (int c4 = 0; c4 < 8; ++c4) {
            const int cc = c4 * 16 + j;
            float e[8];
            #pragma unroll
            for (int t = 0; t < 8; ++t) e[t] = __expf(b2f((uint16_t)x[c4][t]) - mx);
            union { uint32_t w[4]; sh8 v; } pk;
            pk.w[0] = cvtpk(e[0], e[1]); pk.w[1] = cvtpk(e[2], e[3]);
            pk.w[2] = cvtpk(e[4], e[5]); pk.w[3] = cvtpk(e[6], e[7]);
            *(sh8*)&S[rbase + ((cc ^ r) << 3)] = pk.v;
            sum += e[0] + e[1] + e[2] + e[3] + e[4] + e[5] + e[6] + e[7];
        }
        #pragma unroll
        for (int d = 1; d < 16; d <<= 1) sum += __shfl_xor(sum, d);
        if (j == 0) rinv[r] = 1.f / sum;
    }
    __syncthreads();

    // phase 3a: attn global write first, block-linear coalesced (1 KiB/wave/store), NT;
    // stores drain under the PV compute below
    {
        float* ab = attn + ((size_t)((h * BATCH + b) * SEQ + q0)) * SEQ;
        #pragma unroll
        for (int it = 0; it < 16; ++it) {
            const int ch = it * 256 + tid;          // fl4 chunk over 16 rows x 256
            const int row = ch >> 8, oc = ch & 255;
            const int cc = oc >> 1, half = oc & 1;
            const ushort4 p = *(const ushort4*)&S[row * 1024 + ((cc ^ row) << 3) + half * 4];
            const float ri = rinv[row];
            fl4 o;
            o[0] = b2f(p.x) * ri; o[1] = b2f(p.y) * ri;
            o[2] = b2f(p.z) * ri; o[3] = b2f(p.w) * ri;
            __builtin_nontemporal_store(o, (fl4*)(ab + (size_t)ch * 4));
        }
    }

    // phase 3b: ctx = (P_unnorm V) * rinv ; wave wid owns d-block [wid*16, wid*16+16)
    fl4 acc0 = (fl4){0.f, 0.f, 0.f, 0.f}, acc1 = (fl4){0.f, 0.f, 0.f, 0.f};
    const uint16_t* vbase = vT + (size_t)((b * NHEAD + h) * 64 + wid * 16) * SEQ;
    #pragma unroll 4
    for (int ks2 = 0; ks2 < 32; ++ks2) {
        const int kv = ks2 * 32;
        sh8 Ap = *(const sh8*)&S[fr * 1024 + ((((kv + fk) >> 3) ^ fr) << 3)];
        sh8 Bv = *(const sh8*)(vbase + (size_t)fr * SEQ + kv + fk);
        if (ks2 & 1) acc1 = mfma16(Ap, Bv, acc1);
        else         acc0 = mfma16(Ap, Bv, acc0);
    }
    __syncthreads();   // all PV reads of S complete before ctx staging overwrites it

    // phase 4: ctx via 2 KB LDS bounce -> coalesced 8B/lane stores
    {
        uint16_t* Sc = S;
        #pragma unroll
        for (int i = 0; i < 4; ++i) {
            const int qr = frow4 + i;
            Sc[qr * 64 + wid * 16 + fr] = f2bf((acc0[i] + acc1[i]) * rinv[qr]);
        }
        __syncthreads();
        const int row = tid >> 4, c4 = (tid & 15) * 4;
        ushort4 vv = *(ushort4*)&Sc[row * 64 + c4];
        *(ushort4*)(ctx + (size_t)(b * SEQ + q0 + row) * DMODEL + h * 64 + c4) = vv;
    }
}

// ---------------- LayerNorm (in-place): one block per row
__global__ __launch_bounds__(256)
void ln_kernel(const float* __restrict__ raw, const float* __restrict__ gamma,
               const float* __restrict__ beta, float* __restrict__ out) {
    const int row = blockIdx.x;
    const int tid = threadIdx.x;
    const float* x = raw + (size_t)row * DMODEL;
    fl4 xv = *(const fl4*)(x + tid * 4);
    float s  = xv[0] + xv[1] + xv[2] + xv[3];
    float ss = xv[0] * xv[0] + xv[1] * xv[1] + xv[2] * xv[2] + xv[3] * xv[3];
    #pragma unroll
    for (int d = 1; d < 64; d <<= 1) { s += __shfl_xor(s, d); ss += __shfl_xor(ss, d); }
    __shared__ float sb[4], ssb[4];
    if ((tid & 63) == 0) { sb[tid >> 6] = s; ssb[tid >> 6] = ss; }
    __syncthreads();
    s  = sb[0] + sb[1] + sb[2] + sb[3];
    ss = ssb[0] + ssb[1] + ssb[2] + ssb[3];
    const float mu  = s * (1.f / 1024.f);
    const float var = ss * (1.f / 1024.f) - mu * mu;
    const float rstd = rsqrtf(var + 1e-5f);
    fl4 g  = *(const fl4*)(gamma + tid * 4);
    fl4 be = *(const fl4*)(beta + tid * 4);
    fl4 o;
    #pragma unroll
    for (int j = 0; j < 4; ++j) o[j] = (xv[j] - mu) * rstd * g[j] + be[j];
    *(fl4*)(out + (size_t)row * DMODEL + tid * 4) = o;
}

extern "C" void kernel_launch(void* const* d_in, const int* in_sizes, int n_in,
                              void* d_out, int out_size, void* d_ws, size_t ws_size,
                              hipStream_t stream) {
    (void)in_sizes; (void)n_in; (void)out_size; (void)ws_size;
    const float* q     = (const float*)d_in[0];
    const float* k     = (const float*)d_in[1];
    const float* v     = (const float*)d_in[2];
    const uint8_t* mask = (const uint8_t*)d_in[3];
    const float* wq = (const float*)d_in[4];
    const float* bq = (const float*)d_in[5];
    const float* wk = (const float*)d_in[6];
    const float* bk = (const float*)d_in[7];
    const float* wv = (const float*)d_in[8];
    const float* bv = (const float*)d_in[9];
    const float* wo = (const float*)d_in[10];
    const float* bo = (const float*)d_in[11];
    const float* gamma = (const float*)d_in[12];
    const float* beta  = (const float*)d_in[13];

    float* out  = (float*)d_out;
    float* attn = out + (size_t)BATCH * SEQ * DMODEL;

    char* ws = (char*)d_ws;
    uint16_t* qh   = (uint16_t*)(ws);
    uint16_t* kh   = (uint16_t*)(ws + ((size_t)16 << 20));
    uint16_t* vT   = (uint16_t*)(ws + ((size_t)32 << 20));
    uint16_t* ctx  = (uint16_t*)(ws + ((size_t)48 << 20));
    uint16_t* wqT  = (uint16_t*)(ws + ((size_t)64 << 20));
    uint16_t* wkT  = (uint16_t*)(ws + ((size_t)66 << 20));
    uint16_t* wvT  = (uint16_t*)(ws + ((size_t)68 << 20));
    uint16_t* woT  = (uint16_t*)(ws + ((size_t)70 << 20));

    dim3 tb(256);
    prep_kernel<<<dim3(16, 16, 4), tb, 0, stream>>>(wq, wk, wv, wo, wqT, wkT, wvT, woT);

    gemm_proj<<<dim3(64, 8, 3), tb, 0, stream>>>(q, k, v, wqT, wkT, wvT,
                                                 bq, bk, bv, qh, kh, vT);

    attn_kernel<<<dim3(BATCH, NHEAD, 64), tb, 0, stream>>>(qh, kh, vT, mask, attn, ctx);

    gemm_out<<<dim3(64, 8), tb, 0, stream>>>(ctx, woT, bo, q, out);

    ln_kernel<<<BATCH * SEQ, tb, 0, stream>>>(out, gamma, beta, out);
}